// Round 9
// baseline (324.817 us; speedup 1.0000x reference)
//
#include <hip/hip_runtime.h>

#define REP10(X) X(0) X(1) X(2) X(3) X(4) X(5) X(6) X(7) X(8) X(9)

// ---------------------------------------------------------------------------
// prep_kernel: fold BN+conv-bias into scale/shift2; pre-scale attn dw/db by
// log2(e) so softmax uses native v_exp_f32. consts stride 80 per stage:
// [0..10) scale | [10..20) shift2 | [20..70) adw2 | [70..80) adb2
// ---------------------------------------------------------------------------
__device__ __forceinline__ void fold_stage(
    float* dst, const float* g, const float* be, const float* mn,
    const float* vr, const float* cb, const float* adw, const float* adb)
{
  const int tid = threadIdx.x;
  if (tid < 10) {
    const float sc = g[tid] * rsqrtf(vr[tid] + 1e-3f);
    dst[tid]      = sc;
    dst[10 + tid] = (cb[tid] - mn[tid]) * sc + be[tid];
    dst[70 + tid] = adb[tid] * 1.44269504088896340736f;
  }
  if (tid >= 10 && tid < 60)
    dst[10 + tid] = adw[tid - 10] * 1.44269504088896340736f;
}

__global__ void prep_kernel(
    const float* g1, const float* be1, const float* m1, const float* v1,
    const float* cb1, const float* a1dw, const float* a1db,
    const float* g2, const float* be2, const float* m2, const float* v2,
    const float* cb2, const float* a2dw, const float* a2db,
    const float* g3, const float* be3, const float* m3, const float* v3,
    const float* cb3, const float* a3dw, const float* a3db,
    float* consts)
{
  fold_stage(consts,       g1, be1, m1, v1, cb1, a1dw, a1db);
  fold_stage(consts + 80,  g2, be2, m2, v2, cb2, a2dw, a2db);
  fold_stage(consts + 160, g3, be3, m3, v3, cb3, a3dw, a3db);
}

// dnswT[cc][t] = dnsw[t*20+cc]  (makes final_kernel's dns_w loads dwordx4)
__global__ void transpose_dnsw(const float* __restrict__ dnsw,
                               float* __restrict__ dnswT)
{
  const int cc = blockIdx.x;
  for (int t = threadIdx.x; t < 988; t += 256)
    dnswT[cc * 988 + t] = dnsw[t * 20 + cc];
}

// ---------------------------------------------------------------------------
// stage_kernel: one fused VIGNet stage. 4 consecutive t per thread -> all
// data movement is float4 (global_load_dwordx4 / ds_read_b128 / dwordx4
// stores). Block of 256 covers a whole row (Tout%4==0, Tout<=996 -> no
// guards). Named scalars only. grid = (1, 2, batch).
// in : [bc][CIN][2][1000] ; out : [bc][10][2][1000]
// ---------------------------------------------------------------------------
template <int CIN>
__global__ __launch_bounds__(256, 3) void stage_kernel(
    const float* __restrict__ in, float* __restrict__ outp, int Tout,
    const float* __restrict__ ck, const float* __restrict__ aK,
    const float* __restrict__ ab, const float* __restrict__ cst)
{
  __shared__ float smm[10][1004];
  const int tid = threadIdx.x;
  const int o   = blockIdx.y;
  const int Tin = Tout + 4;
  const float* __restrict__ inb = in + (size_t)blockIdx.z * (CIN * 2000);

  // ---- Phase A: einsum m_i for 4 positions per thread -> smm (b128 writes)
  const int ta = tid * 4;
  if (ta < Tin) {   // Tin%4==0 -> full quads only
#define DECLM(i) float m##i##0 = ab[i * 2 + o], m##i##1 = m##i##0,             \
                       m##i##2 = m##i##0, m##i##3 = m##i##0;
    REP10(DECLM)
#undef DECLM
#pragma unroll
    for (int h = 0; h < 2; ++h)
#pragma unroll
      for (int ci = 0; ci < CIN; ++ci) {
        const float4 xv =
            *reinterpret_cast<const float4*>(inb + (ci * 2 + h) * 1000 + ta);
#define FMAM(i) { const float wk_ = aK[((i * 2 + h) * CIN + ci) * 2 + o];      \
        m##i##0 += xv.x * wk_; m##i##1 += xv.y * wk_;                          \
        m##i##2 += xv.z * wk_; m##i##3 += xv.w * wk_; }
        REP10(FMAM)
#undef FMAM
      }
#define STM(i) *reinterpret_cast<float4*>(&smm[i][ta]) =                       \
        make_float4(m##i##0, m##i##1, m##i##2, m##i##3);
    REP10(STM)
#undef STM
  }
  __syncthreads();

  // ---- Phase B: 4 outputs per thread
  const int t = tid * 4;
  if (t >= Tout) return;   // no barriers below

  const float* __restrict__ scale  = cst;
  const float* __restrict__ shift2 = cst + 10;
  const float* __restrict__ adw2   = cst + 20;
  const float* __restrict__ adb2   = cst + 70;

  // attention: depthwise from smm (2x ds_read_b128 per head) + exp2.
  // No max-subtraction: logits here are O(0.1) (weights ~0.1-scale), softmax
  // is shift-invariant, exp2 range is trivially safe.
  float sum0 = 0.f, sum1 = 0.f, sum2 = 0.f, sum3 = 0.f;
#define DECLE(i) float e##i##0, e##i##1, e##i##2, e##i##3;
  REP10(DECLE)
#undef DECLE
#define ATTN(i) {                                                              \
    const float4 sa = *reinterpret_cast<const float4*>(&smm[i][t]);            \
    const float4 sb = *reinterpret_cast<const float4*>(&smm[i][t + 4]);        \
    const float w0 = adw2[i], w1 = adw2[10 + i], w2 = adw2[20 + i],            \
                w3 = adw2[30 + i], w4 = adw2[40 + i];                          \
    const float bi = adb2[i];                                                  \
    const float y0_ = bi + sa.x*w0 + sa.y*w1 + sa.z*w2 + sa.w*w3 + sb.x*w4;    \
    const float y1_ = bi + sa.y*w0 + sa.z*w1 + sa.w*w2 + sb.x*w3 + sb.y*w4;    \
    const float y2_ = bi + sa.z*w0 + sa.w*w1 + sb.x*w2 + sb.y*w3 + sb.z*w4;    \
    const float y3_ = bi + sa.w*w0 + sb.x*w1 + sb.y*w2 + sb.z*w3 + sb.w*w4;    \
    e##i##0 = exp2f(y0_); e##i##1 = exp2f(y1_);                                \
    e##i##2 = exp2f(y2_); e##i##3 = exp2f(y3_);                                \
    sum0 += e##i##0; sum1 += e##i##1; sum2 += e##i##2; sum3 += e##i##3; }
  REP10(ATTN)
#undef ATTN

  // conv (1,5) valid, CIN -> 10: 2x dwordx4 per ci row feeds all 4 outputs
#define DECLA(i) float a0_##i = 0.f, a1_##i = 0.f, a2_##i = 0.f, a3_##i = 0.f;
  REP10(DECLA)
#undef DECLA
  const float* __restrict__ crow = inb + o * 1000 + t;
#pragma unroll
  for (int ci = 0; ci < CIN; ++ci) {
    const float4 xa = *reinterpret_cast<const float4*>(crow + ci * 2000);
    const float4 xb = *reinterpret_cast<const float4*>(crow + ci * 2000 + 4);
#define CONVK(k) { const float* kk = ck + ci * 10 + k;                         \
    const float k0 = kk[0], k1 = kk[CIN * 10], k2 = kk[2 * CIN * 10],          \
                k3 = kk[3 * CIN * 10], k4 = kk[4 * CIN * 10];                  \
    a0_##k += xa.x*k0 + xa.y*k1 + xa.z*k2 + xa.w*k3 + xb.x*k4;                 \
    a1_##k += xa.y*k0 + xa.z*k1 + xa.w*k2 + xb.x*k3 + xb.y*k4;                 \
    a2_##k += xa.z*k0 + xa.w*k1 + xb.x*k2 + xb.y*k3 + xb.z*k4;                 \
    a3_##k += xa.w*k0 + xb.x*k1 + xb.y*k2 + xb.z*k3 + xb.w*k4; }
    REP10(CONVK)
#undef CONVK
  }

  const float r0 = __builtin_amdgcn_rcpf(sum0);
  const float r1 = __builtin_amdgcn_rcpf(sum1);
  const float r2 = __builtin_amdgcn_rcpf(sum2);
  const float r3 = __builtin_amdgcn_rcpf(sum3);

  float* __restrict__ ob = outp + (size_t)blockIdx.z * 20000 + o * 1000 + t;
#define STO(i) { const float sc_ = scale[i], sh_ = shift2[i];                  \
    float b0 = a0_##i * sc_ + sh_; b0 = fmaxf(b0, 0.2f * b0);                  \
    float b1 = a1_##i * sc_ + sh_; b1 = fmaxf(b1, 0.2f * b1);                  \
    float b2 = a2_##i * sc_ + sh_; b2 = fmaxf(b2, 0.2f * b2);                  \
    float b3 = a3_##i * sc_ + sh_; b3 = fmaxf(b3, 0.2f * b3);                  \
    *reinterpret_cast<float4*>(ob + i * 2000) = make_float4(                   \
        b0 * e##i##0 * r0, b1 * e##i##1 * r1,                                  \
        b2 * e##i##2 * r2, b3 * e##i##3 * r3); }
  REP10(STO)
#undef STO
}

// ---------------------------------------------------------------------------
// final_kernel: conv4 (2,1) -> lrelu -> dot(dns_w^T) -> block reduce.
// 4 t per thread, all loads dwordx4 (988 = 4*247).
// ---------------------------------------------------------------------------
__global__ __launch_bounds__(256, 3) void final_kernel(
    const float* __restrict__ h3, const float* __restrict__ c4k,
    const float* __restrict__ c4b, const float* __restrict__ dnswT,
    const float* __restrict__ dnsb, float* __restrict__ outp, int b0)
{
  __shared__ float red[4];
  const int tid = threadIdx.x;
  const float* __restrict__ hb = h3 + (size_t)blockIdx.x * 20000;
  float dot0 = 0.f, dot1 = 0.f, dot2 = 0.f, dot3 = 0.f;
  const int t = tid * 4;
  if (t < 988) {
#define LOADH(i)                                                               \
    const float4 xa##i = *reinterpret_cast<const float4*>(hb + i*2000 + t);    \
    const float4 xb##i = *reinterpret_cast<const float4*>(hb + i*2000 + 1000 + t);
    REP10(LOADH)
#undef LOADH
#pragma unroll 2
    for (int cc = 0; cc < 20; ++cc) {
      const float bias = c4b[cc];
      float a0 = bias, a1 = bias, a2 = bias, a3 = bias;
#define FMA4(i) { const float wA = c4k[i*20 + cc], wB = c4k[(10+i)*20 + cc];   \
      a0 += xa##i.x * wA + xb##i.x * wB; a1 += xa##i.y * wA + xb##i.y * wB;    \
      a2 += xa##i.z * wA + xb##i.z * wB; a3 += xa##i.w * wA + xb##i.w * wB; }
      REP10(FMA4)
#undef FMA4
      a0 = fmaxf(a0, 0.2f * a0); a1 = fmaxf(a1, 0.2f * a1);
      a2 = fmaxf(a2, 0.2f * a2); a3 = fmaxf(a3, 0.2f * a3);
      const float4 dT = *reinterpret_cast<const float4*>(dnswT + cc * 988 + t);
      dot0 += a0 * dT.x; dot1 += a1 * dT.y; dot2 += a2 * dT.z; dot3 += a3 * dT.w;
    }
  }
  float partial = dot0 + dot1 + dot2 + dot3;
#pragma unroll
  for (int off = 32; off > 0; off >>= 1)
    partial += __shfl_down(partial, off, 64);
  if ((tid & 63) == 0) red[tid >> 6] = partial;
  __syncthreads();
  if (tid == 0)
    outp[b0 + blockIdx.x] = red[0] + red[1] + red[2] + red[3] + dnsb[0];
}

extern "C" void kernel_launch(void* const* d_in, const int* in_sizes, int n_in,
                              void* d_out, int out_size, void* d_ws, size_t ws_size,
                              hipStream_t stream) {
  const float* p[35];
  for (int i = 0; i < 35; ++i) p[i] = (const float*)d_in[i];
  const int B = in_sizes[0] / 2000;

  // ws layout: consts[256] | dnswT[19760] | hA | hB   (all float, 16B-aligned)
  float* consts = (float*)d_ws;
  float* dnswT  = consts + 256;
  float* hA     = consts + 20016;
  const size_t avail = ws_size - 20016u * 4u;
  int CH = 1024;
  if (CH > B) CH = B;
  while ((size_t)CH * 160000ull > avail && CH > 1) CH >>= 1;
  float* hB = hA + (size_t)CH * 20000;

  prep_kernel<<<dim3(1), dim3(64), 0, stream>>>(
      p[9], p[10], p[11], p[12], p[2], p[25], p[26],
      p[13], p[14], p[15], p[16], p[4], p[29], p[30],
      p[17], p[18], p[19], p[20], p[6], p[33], p[34],
      consts);
  transpose_dnsw<<<dim3(20), dim3(256), 0, stream>>>(p[21], dnswT);

  for (int b0 = 0; b0 < B; b0 += CH) {
    const int cc = (B - b0 < CH) ? (B - b0) : CH;
    const dim3 blk(256);
    // stage1: x -> hA (Tout=996)
    stage_kernel<1><<<dim3(1, 2, cc), blk, 0, stream>>>(
        p[0] + (size_t)b0 * 2000, hA, 996, p[1], p[23], p[24], consts);
    // stage2: hA -> hB (Tout=992)
    stage_kernel<10><<<dim3(1, 2, cc), blk, 0, stream>>>(
        hA, hB, 992, p[3], p[27], p[28], consts + 80);
    // stage3: hB -> hA (Tout=988)
    stage_kernel<10><<<dim3(1, 2, cc), blk, 0, stream>>>(
        hB, hA, 988, p[5], p[31], p[32], consts + 160);
    // conv4 + dense head
    final_kernel<<<dim3(cc), blk, 0, stream>>>(
        hA, p[7], p[8], dnswT, p[22], (float*)d_out, b0);
  }
}